// Round 8
// baseline (251.321 us; speedup 1.0000x reference)
//
#include <hip/hip_runtime.h>
#include <math.h>

#define EPS 1e-6f

#define B_   16
#define T_   2048
#define LD   256
#define NB   32
#define BT   (B_ * T_)          // 32768
#define NCH  64
#define CHUNK (T_ / NCH)        // 32

typedef short bf16x8 __attribute__((ext_vector_type(8)));
typedef float f32x4  __attribute__((ext_vector_type(4)));

__device__ __forceinline__ unsigned short f2b(float f) {
    unsigned int u = __float_as_uint(f);
    unsigned int r = (u + 0x7fffu + ((u >> 16) & 1u)) >> 16;
    return (unsigned short)r;
}

__device__ __forceinline__ float b2f(unsigned short h) {
    return __uint_as_float(((unsigned int)h) << 16);
}

// XCD-align map (k_tot only): hardware block wg (XCD = wg&7) -> work j with
// (j>>2)&7 == wg&7.  Bijective on [0,1024).
__device__ __forceinline__ int xcd_map(int wg) {
    int x = wg & 7, s = wg >> 3;
    return (s & 3) | (x << 2) | ((s >> 2) << 5);
}

__device__ __forceinline__ bf16x8 frag_ld(const unsigned short* lds, int row, int qd) {
    int pq = qd ^ ((row >> 1) & 3);
    return *(const bf16x8*)(lds + row * 32 + pq * 8);
}

// U buffer chunk: [8 dc][32 i][32 dj] uint32, quad-swizzled within each 128B row:
// physical 8-uint quad p = (dj>>3) ^ (i&3).
__device__ __forceinline__ int u_idx(int i, int d) {
    return ((d >> 5) << 10) + (i << 5) + (((((d >> 3) & 3)) ^ (i & 3)) << 3) + (d & 7);
}

// ---------------------------------------------------------------------------
// k_pre: ALL precompute in one launch, decoded by blockIdx.x (256 thr/block).
// ---------------------------------------------------------------------------
__global__ __launch_bounds__(256) void k_pre(const float* __restrict__ Z,
                                             const float* __restrict__ Dm,
                                             const float* __restrict__ cw,
                                             const float* __restrict__ Ew,
                                             const float* __restrict__ Bw,
                                             const float* __restrict__ Cw,
                                             const float* __restrict__ Mw,
                                             const float* __restrict__ imp,
                                             const float* __restrict__ ilv,
                                             const float* __restrict__ ylv,
                                             unsigned short* __restrict__ GMh,
                                             unsigned short* __restrict__ GCh,
                                             unsigned short* __restrict__ cwbh,
                                             float* __restrict__ im0,
                                             float* __restrict__ iv0,
                                             float* __restrict__ yv,
                                             unsigned short* __restrict__ AbTh,
                                             unsigned short* __restrict__ AbTl,
                                             unsigned short* __restrict__ Bwh,
                                             unsigned short* __restrict__ Zh) {
    int bid = blockIdx.x;
    int tid = threadIdx.x;
    if (bid < 544) {
        // small GEMM: out[f][d] = sum_e W[f][e] * E[e][d]
        const float* W; const float* E; unsigned short* out; int d0, f0;
        if (bid < 256)      { W = Mw; E = Ew; out = GMh;  d0 = (bid & 15) * 16; f0 = (bid >> 4) * 16; }
        else if (bid < 512) { W = Cw; E = Ew; out = GCh;  d0 = (bid & 15) * 16; f0 = ((bid - 256) >> 4) * 16; }
        else                { W = cw; E = Bw; out = cwbh; d0 = (bid & 15) * 16; f0 = ((bid - 512) >> 4) * 16; }
        __shared__ float Ws[16][17];
        __shared__ float Es[16][17];
        int tx = tid & 15, ty = tid >> 4;
        float acc = 0.f;
        for (int eb = 0; eb < LD; eb += 16) {
            Ws[ty][tx] = W[(f0 + ty) * LD + eb + tx];
            Es[ty][tx] = E[(eb + ty) * LD + d0 + tx];
            __syncthreads();
#pragma unroll
            for (int k = 0; k < 16; ++k) acc = fmaf(Ws[ty][k], Es[k][tx], acc);
            __syncthreads();
        }
        out[(f0 + ty) * LD + d0 + tx] = f2b(acc);
    } else if (bid < 577) {
        int sub = bid - 544;
        int t = tid;
        if (sub == 0) {
            float sm = 0.f, sv = 0.f;
            for (int k = 0; k < LD; ++k) {
                float e = Ew[k * LD + t];
                sm = fmaf(e, imp[k], sm);
                sv = fmaf(e * e, expf(ilv[k]) + EPS, sv);
            }
            im0[t] = sm;
            iv0[t] = sv;
            yv[t]  = expf(ylv[t]) + EPS;
        } else {
            int n = sub - 1;
            float a = -(expf(Dm[n * LD + t]) + EPS);
            unsigned short h = f2b(a);
            AbTh[t * NB + n] = h;
            AbTl[t * NB + n] = f2b(a - b2f(h));
        }
    } else if (bid < 641) {
        int i = (bid - 577) * 256 + tid;      // float4 index over 256*256/4
        float4 v = ((const float4*)Bw)[i];
        ((ushort4*)Bwh)[i] = make_ushort4(f2b(v.x), f2b(v.y), f2b(v.z), f2b(v.w));
    } else {
        int i = (bid - 641) * 256 + tid;      // float4 index over BT*LD/4
        float4 v = ((const float4*)Z)[i];
        ((ushort4*)Zh)[i] = make_ushort4(f2b(v.x), f2b(v.y), f2b(v.z), f2b(v.w));
    }
}

// ---------------------------------------------------------------------------
// k_zb: barrier-free / LDS-free.  grid (BT/128, 3).
//  y<2 : alphas[:,y*128:(y+1)*128] = Zh @ Bwh^T   (fp32 out)
//  y==2: logits = Zh @ cwbh^T + cb                (fp32 out, N=32)
// A/B fragments loaded straight from global (L2/L3-resident).
// ---------------------------------------------------------------------------
__global__ __launch_bounds__(256) void k_zb(const unsigned short* __restrict__ Zh,
                                            const unsigned short* __restrict__ Bwh,
                                            const unsigned short* __restrict__ cwbh,
                                            const float* __restrict__ cb,
                                            float* __restrict__ alphas,
                                            float* __restrict__ logits) {
    int tid = threadIdx.x, lane = tid & 63, wv = tid >> 6;
    int qd = lane >> 4, mr = lane & 15;
    int m0 = blockIdx.x * 128;
    int y  = blockIdx.y;
    if (y < 2) {
        int n0 = y * 128;
        int wm = (wv & 1) * 64, wn = (wv >> 1) * 64;
        f32x4 acc[4][4];
#pragma unroll
        for (int i = 0; i < 4; ++i)
#pragma unroll
            for (int j = 0; j < 4; ++j) acc[i][j] = (f32x4){0.f, 0.f, 0.f, 0.f};
        for (int kb = 0; kb < LD; kb += 32) {
            bf16x8 af[4], bf[4];
#pragma unroll
            for (int i = 0; i < 4; ++i)
                af[i] = *(const bf16x8*)(Zh + (size_t)(m0 + wm + i * 16 + mr) * LD + kb + qd * 8);
#pragma unroll
            for (int j = 0; j < 4; ++j)
                bf[j] = *(const bf16x8*)(Bwh + (size_t)(n0 + wn + j * 16 + mr) * LD + kb + qd * 8);
#pragma unroll
            for (int i = 0; i < 4; ++i)
#pragma unroll
                for (int j = 0; j < 4; ++j)
                    acc[i][j] = __builtin_amdgcn_mfma_f32_16x16x32_bf16(af[i], bf[j], acc[i][j], 0, 0, 0);
        }
        int col = wn + mr;
        int rb  = wm + (qd << 2);
#pragma unroll
        for (int i = 0; i < 4; ++i)
#pragma unroll
            for (int j = 0; j < 4; ++j)
#pragma unroll
                for (int r = 0; r < 4; ++r)
                    alphas[(size_t)(m0 + rb + i * 16 + r) * LD + n0 + col + j * 16] = acc[i][j][r];
    } else {
        f32x4 acc[2][2];
#pragma unroll
        for (int i = 0; i < 2; ++i)
#pragma unroll
            for (int j = 0; j < 2; ++j) acc[i][j] = (f32x4){0.f, 0.f, 0.f, 0.f};
        for (int kb = 0; kb < LD; kb += 32) {
            bf16x8 af[2], bff[2];
#pragma unroll
            for (int i = 0; i < 2; ++i)
                af[i] = *(const bf16x8*)(Zh + (size_t)(m0 + wv * 32 + i * 16 + mr) * LD + kb + qd * 8);
#pragma unroll
            for (int j = 0; j < 2; ++j)
                bff[j] = *(const bf16x8*)(cwbh + (size_t)(j * 16 + mr) * LD + kb + qd * 8);
#pragma unroll
            for (int i = 0; i < 2; ++i)
#pragma unroll
                for (int j = 0; j < 2; ++j)
                    acc[i][j] = __builtin_amdgcn_mfma_f32_16x16x32_bf16(af[i], bff[j], acc[i][j], 0, 0, 0);
        }
        int col = mr;
        int rb  = qd << 2;
#pragma unroll
        for (int i = 0; i < 2; ++i)
#pragma unroll
            for (int j = 0; j < 2; ++j)
#pragma unroll
                for (int r = 0; r < 4; ++r) {
                    int row = m0 + wv * 32 + i * 16 + rb + r;
                    int cc  = j * 16 + col;
                    logits[(size_t)row * NB + cc] = acc[i][j][r] + cb[cc];
                }
    }
}

// ---------------------------------------------------------------------------
// k_tot: chunk totals (R6 proven-fast) + AmT export for k_sms.
// AmT layout: [chunk][d][32] fp32 (thread-d-contiguous in i).
// ---------------------------------------------------------------------------
__global__ __launch_bounds__(256) void k_tot(const float* __restrict__ logits,
                                             const float* __restrict__ alphas,
                                             const float* __restrict__ obs,
                                             const unsigned short* __restrict__ AbTh,
                                             const unsigned short* __restrict__ AbTl,
                                             float* __restrict__ AmT,
                                             float* __restrict__ totA,
                                             float* __restrict__ totBm,
                                             float* __restrict__ totBv) {
    __shared__ unsigned int U[8192];
    __shared__ unsigned short Ph[1024];
    __shared__ unsigned short Pl[1024];
    int tid = threadIdx.x;
    int d = tid;
    int bid = xcd_map(blockIdx.x);
    int bt0 = bid * CHUNK;

    // early prefetch: all 32 alphas for this column
    float av[32];
#pragma unroll
    for (int i = 0; i < 32; ++i) av[i] = alphas[(size_t)(bt0 + i) * LD + d];

    // softmax -> Ph/Pl (swizzled)
    int l = tid & 31, rg = tid >> 5;
#pragma unroll
    for (int jj = 0; jj < 4; ++jj) {
        int row = rg * 4 + jj;
        float v = logits[(size_t)(bt0 + row) * NB + l];
        float mx = v;
#pragma unroll
        for (int off = 16; off >= 1; off >>= 1) mx = fmaxf(mx, __shfl_xor(mx, off, 32));
        float e = __expf(v - mx);
        float s = e;
#pragma unroll
        for (int off = 16; off >= 1; off >>= 1) s += __shfl_xor(s, off, 32);
        float p = e * __builtin_amdgcn_rcpf(s);
        unsigned short h = f2b(p);
        unsigned short lo = f2b(p - b2f(h));
        int sa = row * 32 + ((((l >> 3) ^ ((row >> 1) & 3))) << 3) + (l & 7);
        Ph[sa] = h;
        Pl[sa] = lo;
    }
    __syncthreads();

    // Am = P @ AbT^T (3-term hi/lo) -> U (fp32) + AmT export (float4 stores)
    int lane = tid & 63, wv = tid >> 6;
    int qd = lane >> 4, mr = lane & 15;
    bf16x8 ph[2], pl[2];
#pragma unroll
    for (int iT = 0; iT < 2; ++iT) {
        ph[iT] = frag_ld(Ph, iT * 16 + mr, qd);
        pl[iT] = frag_ld(Pl, iT * 16 + mr, qd);
    }
#pragma unroll
    for (int j = 0; j < 4; ++j) {
        int dcol = wv * 64 + j * 16 + mr;
        bf16x8 ah = *(const bf16x8*)(AbTh + dcol * NB + qd * 8);
        bf16x8 al = *(const bf16x8*)(AbTl + dcol * NB + qd * 8);
#pragma unroll
        for (int iT = 0; iT < 2; ++iT) {
            f32x4 acc = (f32x4){0.f, 0.f, 0.f, 0.f};
            acc = __builtin_amdgcn_mfma_f32_16x16x32_bf16(ph[iT], ah, acc, 0, 0, 0);
            acc = __builtin_amdgcn_mfma_f32_16x16x32_bf16(pl[iT], ah, acc, 0, 0, 0);
            acc = __builtin_amdgcn_mfma_f32_16x16x32_bf16(ph[iT], al, acc, 0, 0, 0);
#pragma unroll
            for (int r = 0; r < 4; ++r)
                U[u_idx(iT * 16 + qd * 4 + r, dcol)] = __float_as_uint(acc[r]);
            // AmT[bid][dcol][iT*16 + qd*4 .. +3]  (16B aligned)
            *(f32x4*)(AmT + (size_t)bid * (LD * 32) + (size_t)dcol * 32 + iT * 16 + qd * 4) = acc;
        }
    }
    __syncthreads();

    // scan
    float ra = 1.f, rm = 0.f, rv = 0.f;
    int ubase = ((d >> 5) << 10) + (d & 7);
    int qb = (d >> 3) & 3;
#pragma unroll
    for (int i = 0; i < CHUNK; ++i) {
        int ui = ubase + (i << 5) + ((qb ^ (i & 3)) << 3);
        float Am = __uint_as_float(U[ui]);
        float tt = obs[bt0 + i];
        float eAm = __expf(Am * tt);
        float ieA = __builtin_amdgcn_rcpf(Am);
        float e2  = eAm * eAm;
        float eBm = (eAm - 1.f) * ieA * av[i];
        float eBv = fmaf(0.5f * (e2 - 1.f), ieA, EPS);
        rm = fmaf(eAm, rm, eBm);
        rv = fmaf(e2, rv, eBv);
        ra *= eAm;
    }
    int pidx = bid * LD + d;
    totA[pidx] = ra; totBm[pidx] = rm; totBv[pidx] = rv;
}

// exclusive prefix over chunks per (b,d), batched loads (8 ahead)
__global__ __launch_bounds__(256) void k_chunkpfx(const float* __restrict__ totA,
                                                  const float* __restrict__ totBm,
                                                  const float* __restrict__ totBv,
                                                  float* __restrict__ preA,
                                                  float* __restrict__ preBm,
                                                  float* __restrict__ preBv) {
    int d = threadIdx.x;
    int b = blockIdx.x;
    float Pa = 1.f, Pm = 0.f, Pv = 0.f;
    for (int g = 0; g < 8; ++g) {
        float a8[8], m8[8], v8[8];
#pragma unroll
        for (int k = 0; k < 8; ++k) {
            int pidx = (b * NCH + g * 8 + k) * LD + d;
            a8[k] = totA[pidx]; m8[k] = totBm[pidx]; v8[k] = totBv[pidx];
        }
#pragma unroll
        for (int k = 0; k < 8; ++k) {
            int pidx = (b * NCH + g * 8 + k) * LD + d;
            preA[pidx] = Pa; preBm[pidx] = Pm; preBv[pidx] = Pv;
            Pm = fmaf(a8[k], Pm, m8[k]);
            Pv = fmaf(a8[k] * a8[k], Pv, v8[k]);
            Pa = a8[k] * Pa;
        }
    }
}

// ---------------------------------------------------------------------------
// k_sms: one block = TWO chunks (64 rows).  NO prolog: Am read from AmT
// (written by k_tot).  Two interleaved scan chains -> U (packed mm|ss) ->
// barrier-free MFMA GEMM M=64.  LDS: U 64KB.  One barrier total.
// ---------------------------------------------------------------------------
__global__ __launch_bounds__(256) void k_sms(const float* __restrict__ alphas,
                                             const float* __restrict__ obs,
                                             const float* __restrict__ AmT,
                                             const float* __restrict__ preA,
                                             const float* __restrict__ preBm,
                                             const float* __restrict__ preBv,
                                             const float* __restrict__ im0,
                                             const float* __restrict__ iv0,
                                             const float* __restrict__ yv,
                                             const unsigned short* __restrict__ Zh,
                                             const unsigned short* __restrict__ GMh,
                                             const unsigned short* __restrict__ GCh,
                                             float* __restrict__ means,
                                             float* __restrict__ stds) {
    __shared__ unsigned int U[16384];                 // 64KB: [2 chunks][8 dc][32 i][32 dj]
    int tid = threadIdx.x, lane = tid & 63, wv = tid >> 6;
    int d = tid;
    int bt0 = blockIdx.x * 64;
    int c0  = blockIdx.x * 2;
    int qd = lane >> 4, mr = lane & 15;

    // carries for both chunks (independent scan chains -> 2x ILP)
    int p0 = c0 * LD + d;
    float ga0 = preA[p0],      gm0 = preBm[p0],      gv0 = preBv[p0];
    float ga1 = preA[p0 + LD], gm1 = preBm[p0 + LD], gv1 = preBv[p0 + LD];
    float i0 = im0[d], v0 = iv0[d], yvd = yv[d];

    const float* A0 = AmT + (size_t)c0 * (LD * 32) + (size_t)d * 32;
    const float* A1 = A0 + (size_t)(LD * 32);

    int ubase = ((d >> 5) << 10) + (d & 7);
    int qb = (d >> 3) & 3;
    for (int g = 0; g < 4; ++g) {
        float av0[8], av1[8];
#pragma unroll
        for (int k = 0; k < 8; ++k) {
            av0[k] = alphas[(size_t)(bt0 + g * 8 + k) * LD + d];
            av1[k] = alphas[(size_t)(bt0 + 32 + g * 8 + k) * LD + d];
        }
        f32x4 a0a = *(const f32x4*)(A0 + g * 8);
        f32x4 a0b = *(const f32x4*)(A0 + g * 8 + 4);
        f32x4 a1a = *(const f32x4*)(A1 + g * 8);
        f32x4 a1b = *(const f32x4*)(A1 + g * 8 + 4);
        float am0[8] = {a0a[0], a0a[1], a0a[2], a0a[3], a0b[0], a0b[1], a0b[2], a0b[3]};
        float am1[8] = {a1a[0], a1a[1], a1a[2], a1a[3], a1b[0], a1b[1], a1b[2], a1b[3]};
#pragma unroll
        for (int k = 0; k < 8; ++k) {
            int i = g * 8 + k;
            int ui0 = ubase + (i << 5) + ((qb ^ (i & 3)) << 3);
            int ui1 = 8192 + ui0;
            float Am0 = am0[k];
            float Am1 = am1[k];
            float t0 = obs[bt0 + i];
            float t1 = obs[bt0 + 32 + i];
            float e0 = __expf(Am0 * t0);
            float e1 = __expf(Am1 * t1);
            float r0 = __builtin_amdgcn_rcpf(Am0);
            float r1 = __builtin_amdgcn_rcpf(Am1);
            float q0 = e0 * e0, q1 = e1 * e1;
            float bm0 = (e0 - 1.f) * r0 * av0[k];
            float bm1 = (e1 - 1.f) * r1 * av1[k];
            float bv0 = fmaf(0.5f * (q0 - 1.f), r0, EPS);
            float bv1 = fmaf(0.5f * (q1 - 1.f), r1, EPS);
            gm0 = fmaf(e0, gm0, bm0);   gm1 = fmaf(e1, gm1, bm1);
            gv0 = fmaf(q0, gv0, bv0);   gv1 = fmaf(q1, gv1, bv1);
            ga0 *= e0;                  ga1 *= e1;
            float mm0 = fmaf(ga0, i0, gm0);
            float mm1 = fmaf(ga1, i0, gm1);
            float vv0 = fmaf(ga0 * ga0, v0, gv0) + yvd;
            float vv1 = fmaf(ga1 * ga1, v0, gv1) + yvd;
            float ss0 = sqrtf(vv0);
            float ss1 = sqrtf(vv1);
            U[ui0] = ((unsigned int)f2b(mm0) << 16) | (unsigned int)f2b(ss0);
            U[ui1] = ((unsigned int)f2b(mm1) << 16) | (unsigned int)f2b(ss1);
        }
    }
    __syncthreads();

    // ---- barrier-free MFMA GEMM phase, M=64 ----
    f32x4 accm[4][4], accs[4][4];
#pragma unroll
    for (int iT = 0; iT < 4; ++iT)
#pragma unroll
        for (int j = 0; j < 4; ++j) {
            accm[iT][j] = (f32x4){0.f, 0.f, 0.f, 0.f};
            accs[iT][j] = (f32x4){0.f, 0.f, 0.f, 0.f};
        }
    for (int kc = 0; kc < 8; ++kc) {
        bf16x8 am[4], asv[4], az[4];
#pragma unroll
        for (int iT = 0; iT < 4; ++iT) {
            int row = iT * 16 + mr;                    // 0..63
            int ii = row & 31;
            int off = ((row >> 5) << 13) + (kc << 10) + (ii << 5) + ((qd ^ (ii & 3)) << 3);
            uint4 ua = *(const uint4*)(U + off);
            uint4 ub = *(const uint4*)(U + off + 4);
            unsigned int uu[8] = {ua.x, ua.y, ua.z, ua.w, ub.x, ub.y, ub.z, ub.w};
            bf16x8 m_, s_;
#pragma unroll
            for (int k = 0; k < 8; ++k) {
                m_[k] = (short)(uu[k] >> 16);
                s_[k] = (short)(uu[k] & 0xffffu);
            }
            am[iT] = m_; asv[iT] = s_;
            az[iT] = *(const bf16x8*)(Zh + (size_t)(bt0 + row) * LD + kc * 32 + qd * 8);
        }
#pragma unroll
        for (int j = 0; j < 4; ++j) {
            int brow = wv * 64 + j * 16 + mr;
            bf16x8 bm = *(const bf16x8*)(GMh + (size_t)brow * LD + kc * 32 + qd * 8);
            bf16x8 bc = *(const bf16x8*)(GCh + (size_t)brow * LD + kc * 32 + qd * 8);
#pragma unroll
            for (int iT = 0; iT < 4; ++iT) {
                accm[iT][j] = __builtin_amdgcn_mfma_f32_16x16x32_bf16(am[iT],  bm, accm[iT][j], 0, 0, 0);
                accs[iT][j] = __builtin_amdgcn_mfma_f32_16x16x32_bf16(asv[iT], bm, accs[iT][j], 0, 0, 0);
                accm[iT][j] = __builtin_amdgcn_mfma_f32_16x16x32_bf16(az[iT],  bc, accm[iT][j], 0, 0, 0);
            }
        }
    }

    // ---- epilogue ----
    int col0 = wv * 64 + mr;
    int rb   = (lane >> 4) << 2;
#pragma unroll
    for (int iT = 0; iT < 4; ++iT)
#pragma unroll
        for (int j = 0; j < 4; ++j)
#pragma unroll
            for (int r = 0; r < 4; ++r) {
                size_t off = (size_t)(bt0 + iT * 16 + rb + r) * LD + col0 + j * 16;
                means[off] = accm[iT][j][r];
                stds[off]  = accs[iT][j][r];
            }
}

// ---------------------------------------------------------------------------
extern "C" void kernel_launch(void* const* d_in, const int* in_sizes, int n_in,
                              void* d_out, int out_size, void* d_ws, size_t ws_size,
                              hipStream_t stream) {
    const float* Z   = (const float*)d_in[0];
    const float* obs = (const float*)d_in[1];
    const float* Dm  = (const float*)d_in[2];
    const float* cw  = (const float*)d_in[3];
    const float* cb  = (const float*)d_in[4];
    const float* Ew  = (const float*)d_in[5];
    const float* Bw  = (const float*)d_in[6];
    const float* Cw  = (const float*)d_in[7];
    const float* Mw  = (const float*)d_in[8];
    const float* imp = (const float*)d_in[9];
    const float* ilv = (const float*)d_in[10];
    const float* ylv = (const float*)d_in[11];

    float* out    = (float*)d_out;
    float* means  = out;
    float* stds   = out + (size_t)BT * LD;
    float* alphas = out + (size_t)2 * BT * LD;

    char* ws = (char*)d_ws;
    size_t o = 0;
    unsigned short* Zh   = (unsigned short*)(ws + o); o += (size_t)BT * LD * 2;   // 16MB
    float*          logits=(float*)(ws + o);          o += (size_t)BT * NB * 4;   // 4MB
    float*          AmT  = (float*)(ws + o);          o += (size_t)BT * LD * 4;   // 33.5MB
    unsigned short* GMh  = (unsigned short*)(ws + o); o += (size_t)LD * LD * 2;
    unsigned short* GCh  = (unsigned short*)(ws + o); o += (size_t)LD * LD * 2;
    unsigned short* Bwh  = (unsigned short*)(ws + o); o += (size_t)LD * LD * 2;
    unsigned short* cwbh = (unsigned short*)(ws + o); o += (size_t)NB * LD * 2;
    unsigned short* AbTh = (unsigned short*)(ws + o); o += (size_t)LD * NB * 2;
    unsigned short* AbTl = (unsigned short*)(ws + o); o += (size_t)LD * NB * 2;
    float* totA  = (float*)(ws + o); o += (size_t)B_ * NCH * LD * 4;
    float* totBm = (float*)(ws + o); o += (size_t)B_ * NCH * LD * 4;
    float* totBv = (float*)(ws + o); o += (size_t)B_ * NCH * LD * 4;
    float* preA  = (float*)(ws + o); o += (size_t)B_ * NCH * LD * 4;
    float* preBm = (float*)(ws + o); o += (size_t)B_ * NCH * LD * 4;
    float* preBv = (float*)(ws + o); o += (size_t)B_ * NCH * LD * 4;
    float* im0   = (float*)(ws + o); o += LD * 4;
    float* iv0   = (float*)(ws + o); o += LD * 4;
    float* yv    = (float*)(ws + o); o += LD * 4;

    // 1. all precompute
    k_pre<<<dim3(641 + BT * LD / 1024), dim3(256), 0, stream>>>(
        Z, Dm, cw, Ew, Bw, Cw, Mw, imp, ilv, ylv,
        GMh, GCh, cwbh, im0, iv0, yv, AbTh, AbTl, Bwh, Zh);

    // 2. alphas + logits (both straight from Zh)
    k_zb<<<dim3(BT / 128, 3), dim3(256), 0, stream>>>(Zh, Bwh, cwbh, cb, alphas, logits);

    // 3-4. chunk totals (+ AmT export) + prefix
    k_tot<<<dim3(B_ * NCH), dim3(256), 0, stream>>>(logits, alphas, obs, AbTh, AbTl,
                                                    AmT, totA, totBm, totBv);
    k_chunkpfx<<<dim3(B_), dim3(LD), 0, stream>>>(totA, totBm, totBv, preA, preBm, preBv);

    // 5. fused scan + means/stds GEMMs (one block = 2 chunks, no prolog)
    k_sms<<<dim3(B_ * NCH / 2), dim3(256), 0, stream>>>(alphas, obs, AmT,
                                                        preA, preBm, preBv,
                                                        im0, iv0, yv,
                                                        Zh, GMh, GCh, means, stds);
}